// Round 4
// baseline (2178.942 us; speedup 1.0000x reference)
//
#include <hip/hip_runtime.h>
#include <cstddef>

#define T_STEPS 512
#define BATCH   64
#define EDIM    512
#define HDIM    512
#define ODIM    512

#define W_ELEMS  (32 * 4 * 64 * 8)  // W kt 0..3: 65536 elems = 131072 B
#define HB_ELEMS (16 * 512)         // one h buffer: 8192 elems = 16384 B

typedef __bf16 bf16;
typedef __bf16 bf16x4 __attribute__((ext_vector_type(4)));
typedef __bf16 bf16x8 __attribute__((ext_vector_type(8)));
typedef float  f32x4  __attribute__((ext_vector_type(4)));

// LDS-only barrier: does NOT drain vmcnt, so in-flight global loads/stores
// (A prefetch, Hbf stores) ride across it. rule-18 fence: sched_barrier after.
__device__ __forceinline__ void barrier_lds() {
  asm volatile("s_waitcnt lgkmcnt(0)\n\ts_barrier" ::: "memory");
  __builtin_amdgcn_sched_barrier(0);
}

// ---------------------------------------------------------------------------
// MFMA GEMM (proven r0-r3): C[r,n] = sum_k X[r,k] * W[n, kw0+k] + bias[n]
// 128x128 tile, BK=32, 4 waves. REMAP (proven): rows b*T+t -> t*B+b.
// ---------------------------------------------------------------------------
template <typename XT, bool REMAP>
__global__ __launch_bounds__(256) void gemm_mfma_kernel(
    const XT* __restrict__ X, int ldx,
    const float* __restrict__ W, int ldw, int kw0,
    const float* __restrict__ bias,
    float* __restrict__ C, int ldc, int K)
{
  __shared__ __align__(16) bf16 Asm[8 * 64 * 8];
  __shared__ __align__(16) bf16 Bsm[8 * 64 * 8];

  const int tid  = threadIdx.x;
  const int row0 = blockIdx.x * 128;
  const int col0 = blockIdx.y * 128;
  const int w    = tid >> 6, lane = tid & 63;
  const int q    = lane >> 4, nl = lane & 15;
  const int wm   = w >> 1, wn = w & 1;

  f32x4 acc[4][4] = {};

  for (int k0 = 0; k0 < K; k0 += 32) {
#pragma unroll
    for (int rep = 0; rep < 2; ++rep) {
      int idx = tid + rep * 256;
      int mt = idx >> 6, l2 = idx & 63;
      const XT* src = X + (size_t)(row0 + mt * 16 + (l2 & 15)) * ldx
                        + k0 + (l2 >> 4) * 8;
      bf16x8 v;
#pragma unroll
      for (int u = 0; u < 8; ++u) v[u] = (bf16)(float)src[u];
      *(bf16x8*)&Asm[(size_t)idx * 8] = v;
    }
#pragma unroll
    for (int rep = 0; rep < 2; ++rep) {
      int idx = tid + rep * 256;
      int nt = idx >> 6, l2 = idx & 63;
      const float* src = W + (size_t)(col0 + nt * 16 + (l2 & 15)) * ldw
                           + kw0 + k0 + (l2 >> 4) * 8;
      bf16x8 v;
#pragma unroll
      for (int u = 0; u < 8; ++u) v[u] = (bf16)src[u];
      *(bf16x8*)&Bsm[(size_t)idx * 8] = v;
    }
    __syncthreads();

    bf16x8 a[4], b[4];
#pragma unroll
    for (int i = 0; i < 4; ++i)
      a[i] = *(bf16x8*)&Asm[(size_t)((wm * 4 + i) * 64 + lane) * 8];
#pragma unroll
    for (int j = 0; j < 4; ++j)
      b[j] = *(bf16x8*)&Bsm[(size_t)((wn * 4 + j) * 64 + lane) * 8];
#pragma unroll
    for (int i = 0; i < 4; ++i)
#pragma unroll
      for (int j = 0; j < 4; ++j)
        acc[i][j] = __builtin_amdgcn_mfma_f32_16x16x32_bf16(a[i], b[j], acc[i][j], 0, 0, 0);
    __syncthreads();
  }

#pragma unroll
  for (int i = 0; i < 4; ++i)
#pragma unroll
    for (int j = 0; j < 4; ++j) {
      int colg = col0 + wn * 64 + j * 16 + nl;
#pragma unroll
      for (int r = 0; r < 4; ++r) {
        size_t rowg = (size_t)(row0 + wm * 64 + i * 16 + q * 4 + r);
        size_t crow = REMAP ? (((rowg & (T_STEPS - 1)) << 6) | (rowg >> 9)) : rowg;
        C[crow * ldc + colg] = acc[i][j][r] + bias[colg];
      }
    }
}

// ---------------------------------------------------------------------------
// Scan, round-4: 4 WGs x 256 threads = 4 waves at 1 wave/SIMD (512-VGPR
// budget). r3 post-mortem: step time = LDS traffic (272 KB/step) + MFMA,
// nearly serial; af (h-frag) reads are pure broadcast redundancy ~#waves.
// Halve the waves -> af traffic halves (128->64 KB/step); Wlds 128 KB/step
// is the floor (W=512 KB total, 384 KB now in regs).
//   wave w owns cols n0 = w*128 (8 n-tiles); Wreg[8][12] = 384 VGPR holds
//   kt 4..15; kt 0..3 from LDS. acc[8]=32, An[8]=32 regs.
// All layouts r2/r3-proven (operand-swapped MFMA):
//   W (A-op): lane (q,nl) holds W1[ntile+nl][kt*32 + q*8 + u]
//   h (B-op): lane (q,nl) holds h[row nl][kt*32 + q*8 + u]
//   D:        lane (q,nl) holds h_t[row nl][cols ntile + q*4 .. +3]
// Double-buffered h + single LDS-only barrier per step (r3-proven).
// ---------------------------------------------------------------------------
template <int DBUF>
__global__ __launch_bounds__(256, 1) void scan_kernel(
    const float* __restrict__ A,     // [T, B, H] fp32 (t-major, REMAP GEMM)
    const float* __restrict__ W1,    // [H, E+H] fp32
    bf16* __restrict__ Hbf)          // [B, T, H] bf16
{
  extern __shared__ __align__(16) bf16 smem[];
  bf16* Wlds = smem;                       // [tg(32)][kt(4)][lane(64)][8]
  bf16* hb0  = smem + W_ELEMS;             // [16][512] swizzled
  bf16* hb1  = DBUF ? (hb0 + HB_ELEMS) : hb0;

  const int tid  = threadIdx.x;
  const int c    = blockIdx.x;
  const int w    = tid >> 6, lane = tid & 63;
  const int q    = lane >> 4, nl = lane & 15;
  const int rb0  = c * 16;
  const int n0   = w * 128;                // 8 n-tiles per wave
  const int sw   = (nl & 7) << 3;          // elem-granularity row swizzle

  // ---- one-time: W kt 0..3, all 32 n-tiles -> LDS ------------------------
  for (int idx = tid; idx < 32 * 4 * 64; idx += 256) {
    int l  = idx & 63;
    int kt = (idx >> 6) & 3;
    int tg = idx >> 8;
    int n  = tg * 16 + (l & 15);
    int k  = kt * 32 + (l >> 4) * 8;
    const float* src = W1 + (size_t)n * (EDIM + HDIM) + EDIM + k;
    bf16x8 v;
#pragma unroll
    for (int u = 0; u < 8; ++u) v[u] = (bf16)src[u];
    *(bf16x8*)&Wlds[(size_t)idx * 8] = v;
  }

  // ---- one-time: W kt 4..15 for this wave's 8 tiles -> 384 VGPRs ---------
  bf16x8 Wreg[8][12];
#pragma unroll
  for (int i = 0; i < 8; ++i) {
    const float* wrow = W1 + (size_t)(n0 + i * 16 + nl) * (EDIM + HDIM) + EDIM + q * 8;
#pragma unroll
    for (int kt2 = 0; kt2 < 12; ++kt2) {
      const float* src = wrow + (kt2 + 4) * 32;
      bf16x8 v;
#pragma unroll
      for (int u = 0; u < 8; ++u) v[u] = (bf16)src[u];
      Wreg[i][kt2] = v;
    }
  }
  __syncthreads();

  // ---- prefetch A_0 (8x f32x4; t-major A; proven mapping) ----------------
  f32x4 An[8];
  {
    const float* ap = A + (size_t)(rb0 + nl) * HDIM + n0 + q * 4;
#pragma unroll
    for (int i = 0; i < 8; ++i) An[i] = *(const f32x4*)(ap + i * 16);
  }

  f32x4 acc[8];

  for (int t = 0; t < T_STEPS; ++t) {
    bf16* hr = (t & 1) ? hb1 : hb0;
    bf16* hw = (t & 1) ? hb0 : hb1;

    // ---- acc init from prefetched A_t; issue A_{t+1} prefetch ------------
#pragma unroll
    for (int i = 0; i < 8; ++i) acc[i] = An[i];
    {
      int tn = (t + 1 < T_STEPS) ? t + 1 : 0;
      const float* ap = A + ((size_t)tn * BATCH + rb0 + nl) * HDIM + n0 + q * 4;
#pragma unroll
      for (int i = 0; i < 8; ++i) An[i] = *(const f32x4*)(ap + i * 16);
    }

    // ---- h_{t-1} @ W1h^T over K=512 (operand-swapped MFMA) ---------------
    if (t > 0) {
      const bf16* hrow = hr + nl * 512;
#pragma unroll
      for (int kt = 0; kt < 16; ++kt) {
        bf16x8 af = *(bf16x8*)&hrow[(kt * 32 + q * 8) ^ sw];
        if (kt < 4) {
#pragma unroll
          for (int i = 0; i < 8; ++i) {
            bf16x8 wb = *(bf16x8*)&Wlds[(size_t)(((w * 8 + i) * 4 + kt) * 64 + lane) * 8];
            acc[i] = __builtin_amdgcn_mfma_f32_16x16x32_bf16(wb, af, acc[i], 0, 0, 0);
          }
        } else {
#pragma unroll
          for (int i = 0; i < 8; ++i)
            acc[i] = __builtin_amdgcn_mfma_f32_16x16x32_bf16(Wreg[i][kt - 4], af, acc[i], 0, 0, 0);
        }
      }
    }

    if (!DBUF) barrier_lds();   // single-buffer WAR: reads done before overwrite

    // ---- relu; write h_t to hw (swizzled) + Hbf directly from regs -------
    {
      bf16* dstg = Hbf + ((size_t)(rb0 + nl) * T_STEPS + t) * HDIM + n0 + q * 4;
#pragma unroll
      for (int i = 0; i < 8; ++i) {
        bf16x4 hv;
#pragma unroll
        for (int r = 0; r < 4; ++r) {
          float v = acc[i][r] > 0.0f ? acc[i][r] : 0.0f;
          hv[r] = (bf16)v;
        }
        *(bf16x4*)&hw[nl * 512 + ((n0 + i * 16 + q * 4) ^ sw)] = hv;
        *(bf16x4*)(dstg + i * 16) = hv;
      }
    }

    barrier_lds();   // h_t visible; orders reads-of-hr vs next-step writes
  }
}

// ---------------------------------------------------------------------------
__global__ __launch_bounds__(256) void copy_hfinal_kernel(
    const bf16* __restrict__ Hbf, float* __restrict__ out)
{
  int i = blockIdx.x * blockDim.x + threadIdx.x;
  int b = i / HDIM, n = i % HDIM;
  out[i] = (float)Hbf[((size_t)b * T_STEPS + (T_STEPS - 1)) * HDIM + n];
}

extern "C" void kernel_launch(void* const* d_in, const int* in_sizes, int n_in,
                              void* d_out, int out_size, void* d_ws, size_t ws_size,
                              hipStream_t stream) {
  const float* x  = (const float*)d_in[0];
  const float* W1 = (const float*)d_in[1];
  const float* b1 = (const float*)d_in[2];
  const float* W2 = (const float*)d_in[3];
  const float* b2 = (const float*)d_in[4];

  float* out = (float*)d_out;
  float* A   = out;   // fp32 x-projection staged in d_out ([T,B,H] order);
                      // consumed by the scan before GEMM3 overwrites it

  bf16* Hbf  = (bf16*)d_ws;   // 32 MB

  // 1) A = X @ W1[:, :E]^T + b1  (bf16 MFMA, fp32 out, rows remapped to [T,B])
  {
    dim3 grid(BATCH * T_STEPS / 128, HDIM / 128);
    gemm_mfma_kernel<float, true><<<grid, 256, 0, stream>>>(
        x, EDIM, W1, EDIM + HDIM, 0, b1, A, HDIM, EDIM);
  }

  // 2) scan: 4 waves, 1 wave/SIMD, 512-VGPR budget. DBUF = 163840 B dynamic
  // LDS (exactly 160 KiB); deterministic fallback to single-buffer variant.
  {
    int smem_dbuf = (W_ELEMS + 2 * HB_ELEMS) * 2;   // 163840
    int smem_sbuf = (W_ELEMS + 1 * HB_ELEMS) * 2;   // 147456
    hipError_t e = hipFuncSetAttribute(
        reinterpret_cast<const void*>(scan_kernel<1>),
        hipFuncAttributeMaxDynamicSharedMemorySize, smem_dbuf);
    if (e == hipSuccess) {
      scan_kernel<1><<<4, 256, smem_dbuf, stream>>>(A, W1, Hbf);
    } else {
      hipFuncSetAttribute(
          reinterpret_cast<const void*>(scan_kernel<0>),
          hipFuncAttributeMaxDynamicSharedMemorySize, smem_sbuf);
      scan_kernel<0><<<4, 256, smem_sbuf, stream>>>(A, W1, Hbf);
    }
  }

  // 3) outs = Hbf @ W2^T + b2 (overwrites the A staging area)
  {
    dim3 grid(BATCH * T_STEPS / 128, ODIM / 128);
    gemm_mfma_kernel<bf16, false><<<grid, 256, 0, stream>>>(
        Hbf, HDIM, W2, HDIM, 0, b2, out, ODIM, HDIM);
  }

  // 4) h_final tail
  copy_hfinal_kernel<<<(BATCH * HDIM) / 256, 256, 0, stream>>>(
      Hbf, out + (size_t)BATCH * T_STEPS * ODIM);
}